// Round 2
// baseline (412.445 us; speedup 1.0000x reference)
//
#include <hip/hip_runtime.h>

#define BN_EPS 0.001f

// deg[i] = number of edges with src == i
__global__ __launch_bounds__(256) void k_deg(const int2* __restrict__ ei,
                                             int* __restrict__ deg, int E) {
  int e = blockIdx.x * 256 + threadIdx.x;
  if (e < E) atomicAdd(&deg[ei[e].x], 1);
}

// h = X @ W + b   (X: N x 128 f32, W: 128 x 64 f32, h: N x 64 f32)
__global__ __launch_bounds__(256) void k_gemm(const float* __restrict__ X,
                                              const float* __restrict__ W,
                                              const float* __restrict__ B,
                                              float* __restrict__ h, int N) {
  __shared__ float Ws[128 * 64];      // 32 KB
  __shared__ float Xs[16 * 132];      // padded stride 132 breaks bank conflicts
  int tid = threadIdx.x;

  // stage W -> LDS
  const float4* W4 = (const float4*)W;
  for (int i = tid; i < (128 * 64) / 4; i += 256) {
    *(float4*)&Ws[i * 4] = W4[i];
  }

  int row0 = blockIdx.x * 16;
  const float4* X4 = (const float4*)(X + (size_t)row0 * 128);
  int avail = (N - row0) * 128;       // valid elements in this 16-row tile
  for (int i = tid * 4; i < 16 * 128; i += 1024) {
    int r = i >> 7, c = i & 127;
    float4 v;
    if (i + 3 < avail) v = X4[i / 4];
    else               v = make_float4(0.f, 0.f, 0.f, 0.f);
    *(float4*)&Xs[r * 132 + c] = v;
  }
  __syncthreads();

  int r  = tid >> 4;           // 0..15 row within tile
  int c4 = (tid & 15) * 4;     // 0..60 column group
  float a0 = B[c4 + 0], a1 = B[c4 + 1], a2 = B[c4 + 2], a3 = B[c4 + 3];

  #pragma unroll
  for (int k = 0; k < 128; k += 4) {
    float4 xv = *(const float4*)&Xs[r * 132 + k];
    float4 w0 = *(const float4*)&Ws[(k + 0) * 64 + c4];
    float4 w1 = *(const float4*)&Ws[(k + 1) * 64 + c4];
    float4 w2 = *(const float4*)&Ws[(k + 2) * 64 + c4];
    float4 w3 = *(const float4*)&Ws[(k + 3) * 64 + c4];
    a0 = fmaf(xv.x, w0.x, a0); a1 = fmaf(xv.x, w0.y, a1);
    a2 = fmaf(xv.x, w0.z, a2); a3 = fmaf(xv.x, w0.w, a3);
    a0 = fmaf(xv.y, w1.x, a0); a1 = fmaf(xv.y, w1.y, a1);
    a2 = fmaf(xv.y, w1.z, a2); a3 = fmaf(xv.y, w1.w, a3);
    a0 = fmaf(xv.z, w2.x, a0); a1 = fmaf(xv.z, w2.y, a1);
    a2 = fmaf(xv.z, w2.z, a2); a3 = fmaf(xv.z, w2.w, a3);
    a0 = fmaf(xv.w, w3.x, a0); a1 = fmaf(xv.w, w3.y, a1);
    a2 = fmaf(xv.w, w3.z, a2); a3 = fmaf(xv.w, w3.w, a3);
  }

  int row = row0 + r;
  if (row < N) {
    *(float4*)&h[(size_t)row * 64 + c4] = make_float4(a0, a1, a2, a3);
  }
}

// agg[src] += inv_sqrt_deg[src]*inv_sqrt_deg[dst] * h[dst]  (one lane per (edge,feature))
__global__ __launch_bounds__(256) void k_agg(const int2* __restrict__ ei,
                                             const int* __restrict__ deg,
                                             const float* __restrict__ h,
                                             float* __restrict__ agg, int E) {
  long long t = (long long)blockIdx.x * 256 + threadIdx.x;
  int e    = (int)(t >> 6);
  int lane = (int)(t & 63);
  if (e >= E) return;
  int2 sd = ei[e];
  float scale = rsqrtf((float)deg[sd.x]) * rsqrtf((float)deg[sd.y]);
  float v = h[(size_t)sd.y * 64 + lane];
  atomicAdd(&agg[(size_t)sd.x * 64 + lane], scale * v);
}

// out = BN(0.5*agg + 0.5*deg*h)   (self_sum/max(deg,1) == deg*h for integer deg>=1)
__global__ __launch_bounds__(256) void k_final(const float* __restrict__ agg,
                                               const float* __restrict__ h,
                                               const int* __restrict__ deg,
                                               const float* __restrict__ gamma,
                                               const float* __restrict__ beta,
                                               const float* __restrict__ mean,
                                               const float* __restrict__ var,
                                               float* __restrict__ out, int N) {
  long long t = (long long)blockIdx.x * 256 + threadIdx.x;
  size_t idx = (size_t)t * 4;
  if (idx >= (size_t)N * 64) return;
  int i = (int)(idx >> 6);
  int j = (int)(idx & 63);
  float d = (float)deg[i];
  float sm = (d > 0.f) ? d : 0.f;
  float4 ag = *(const float4*)&agg[idx];
  float4 hv = *(const float4*)&h[idx];

  float r0 = 0.5f * ag.x + 0.5f * sm * hv.x;
  float r1 = 0.5f * ag.y + 0.5f * sm * hv.y;
  float r2 = 0.5f * ag.z + 0.5f * sm * hv.z;
  float r3 = 0.5f * ag.w + 0.5f * sm * hv.w;

  float g0 = gamma[j + 0] * rsqrtf(var[j + 0] + BN_EPS);
  float g1 = gamma[j + 1] * rsqrtf(var[j + 1] + BN_EPS);
  float g2 = gamma[j + 2] * rsqrtf(var[j + 2] + BN_EPS);
  float g3 = gamma[j + 3] * rsqrtf(var[j + 3] + BN_EPS);

  float4 o;
  o.x = (r0 - mean[j + 0]) * g0 + beta[j + 0];
  o.y = (r1 - mean[j + 1]) * g1 + beta[j + 1];
  o.z = (r2 - mean[j + 2]) * g2 + beta[j + 2];
  o.w = (r3 - mean[j + 3]) * g3 + beta[j + 3];
  *(float4*)&out[idx] = o;
}

extern "C" void kernel_launch(void* const* d_in, const int* in_sizes, int n_in,
                              void* d_out, int out_size, void* d_ws, size_t ws_size,
                              hipStream_t stream) {
  const float* X     = (const float*)d_in[0];
  const float* W     = (const float*)d_in[1];
  const float* B     = (const float*)d_in[2];
  const float* gamma = (const float*)d_in[3];
  const float* beta  = (const float*)d_in[4];
  const float* mean  = (const float*)d_in[5];
  const float* var   = (const float*)d_in[6];
  const int2*  ei    = (const int2*)d_in[7];

  int N = in_sizes[0] / 128;
  int E = in_sizes[7] / 2;

  float* h   = (float*)d_ws;                       // N*64 fp32
  float* agg = h + (size_t)N * 64;                 // N*64 fp32
  int*   deg = (int*)(agg + (size_t)N * 64);       // N int32
  float* out = (float*)d_out;

  hipMemsetAsync(deg, 0, (size_t)N * sizeof(int), stream);
  hipMemsetAsync(agg, 0, (size_t)N * 64 * sizeof(float), stream);

  k_deg<<<(E + 255) / 256, 256, 0, stream>>>(ei, deg, E);
  k_gemm<<<(N + 15) / 16, 256, 0, stream>>>(X, W, B, h, N);

  long long tot = (long long)E * 64;
  k_agg<<<(int)((tot + 255) / 256), 256, 0, stream>>>(ei, deg, h, agg, E);

  int tot2 = N * 16;  // N*64/4 threads
  k_final<<<(tot2 + 255) / 256, 256, 0, stream>>>(agg, h, deg, gamma, beta, mean, var, out, N);
}

// Round 3
// 330.842 us; speedup vs baseline: 1.2467x; 1.2467x over previous
//
#include <hip/hip_runtime.h>

#define BN_EPS 0.001f

// ---------- deg[i] = #edges with src == i ----------
__global__ __launch_bounds__(256) void k_deg(const int2* __restrict__ ei,
                                             int* __restrict__ deg, int E) {
  int e = blockIdx.x * 256 + threadIdx.x;
  if (e < E) atomicAdd(&deg[ei[e].x], 1);
}

// ---------- scan stage A: per-block (1024 elems) local exclusive scan + block totals + isd ----------
__global__ __launch_bounds__(256) void k_scanA(const int* __restrict__ deg,
                                               int* __restrict__ starts,
                                               int* __restrict__ blocksum,
                                               float* __restrict__ isd, int N) {
  __shared__ int sdata[256];
  int tid = threadIdx.x;
  int base = blockIdx.x * 1024 + tid * 4;
  int v0 = 0, v1 = 0, v2 = 0, v3 = 0;
  if (base + 3 < N) {
    int4 d = *(const int4*)&deg[base];
    v0 = d.x; v1 = d.y; v2 = d.z; v3 = d.w;
  } else {
    if (base     < N) v0 = deg[base];
    if (base + 1 < N) v1 = deg[base + 1];
    if (base + 2 < N) v2 = deg[base + 2];
    if (base + 3 < N) v3 = deg[base + 3];
  }
  if (base     < N) isd[base]     = rsqrtf((float)max(v0, 1));
  if (base + 1 < N) isd[base + 1] = rsqrtf((float)max(v1, 1));
  if (base + 2 < N) isd[base + 2] = rsqrtf((float)max(v2, 1));
  if (base + 3 < N) isd[base + 3] = rsqrtf((float)max(v3, 1));

  int s4 = v0 + v1 + v2 + v3;
  sdata[tid] = s4;
  __syncthreads();
  for (int off = 1; off < 256; off <<= 1) {
    int t = (tid >= off) ? sdata[tid - off] : 0;
    __syncthreads();
    sdata[tid] += t;
    __syncthreads();
  }
  int incl = sdata[tid];
  int excl = incl - s4;
  if (tid == 255) blocksum[blockIdx.x] = incl;
  if (base     < N) starts[base]     = excl;
  if (base + 1 < N) starts[base + 1] = excl + v0;
  if (base + 2 < N) starts[base + 2] = excl + v0 + v1;
  if (base + 3 < N) starts[base + 3] = excl + v0 + v1 + v2;
}

// ---------- scan stage B: single-block exclusive scan of block totals ----------
__global__ __launch_bounds__(256) void k_scanB(const int* __restrict__ blocksum,
                                               int* __restrict__ blockoff, int nb) {
  __shared__ int sdata[256];
  int tid = threadIdx.x;
  int carry = 0;
  for (int c0 = 0; c0 < nb; c0 += 256) {
    int i = c0 + tid;
    int v = (i < nb) ? blocksum[i] : 0;
    sdata[tid] = v;
    __syncthreads();
    for (int off = 1; off < 256; off <<= 1) {
      int t = (tid >= off) ? sdata[tid - off] : 0;
      __syncthreads();
      sdata[tid] += t;
      __syncthreads();
    }
    if (i < nb) blockoff[i] = carry + sdata[tid] - v;
    carry += sdata[255];
    __syncthreads();
  }
}

// ---------- combine: off[i] = starts[i] + blockoff[i/1024]; off[N] = E ----------
__global__ __launch_bounds__(256) void k_offsets(const int* __restrict__ starts,
                                                 const int* __restrict__ blockoff,
                                                 int* __restrict__ off, int N, int E) {
  int i = blockIdx.x * 256 + threadIdx.x;
  if (i < N) off[i] = starts[i] + blockoff[i >> 10];
  else if (i == N) off[N] = E;
}

// ---------- scatter edges into CSR-by-src ----------
__global__ __launch_bounds__(256) void k_scatter(const int2* __restrict__ ei,
                                                 const int* __restrict__ off,
                                                 int* __restrict__ cursor,
                                                 int* __restrict__ csr, int E) {
  int e = blockIdx.x * 256 + threadIdx.x;
  if (e >= E) return;
  int2 sd = ei[e];
  int pos = off[sd.x] + atomicAdd(&cursor[sd.x], 1);
  csr[pos] = sd.y;
}

// ---------- h = X @ W + b  (64-row tiles, 4x4 register blocking) ----------
__global__ __launch_bounds__(256) void k_gemm(const float* __restrict__ X,
                                              const float* __restrict__ W,
                                              const float* __restrict__ B,
                                              float* __restrict__ h, int N) {
  __shared__ float Ws[128 * 64];   // 32 KB
  __shared__ float Xs[64 * 132];   // 33.8 KB, stride 132 breaks bank conflicts
  int tid = threadIdx.x;

  const float4* W4 = (const float4*)W;
  for (int i = tid; i < 2048; i += 256) *(float4*)&Ws[i * 4] = W4[i];

  int row0 = blockIdx.x * 64;
  const float4* X4 = (const float4*)(X + (size_t)row0 * 128);
  int avail = (N - row0) * 128;
  for (int i = tid * 4; i < 8192; i += 1024) {
    int r = i >> 7, c = i & 127;
    float4 v = (i + 3 < avail) ? X4[i >> 2] : make_float4(0.f, 0.f, 0.f, 0.f);
    *(float4*)&Xs[r * 132 + c] = v;
  }
  __syncthreads();

  int tx = tid & 15, ty = tid >> 4;
  int c4 = tx * 4;
  int rbase = ty * 4;
  float4 bb = *(const float4*)&B[c4];
  float4 acc[4];
  acc[0] = bb; acc[1] = bb; acc[2] = bb; acc[3] = bb;

  #pragma unroll 4
  for (int k = 0; k < 128; k += 4) {
    float4 w0 = *(const float4*)&Ws[(k + 0) * 64 + c4];
    float4 w1 = *(const float4*)&Ws[(k + 1) * 64 + c4];
    float4 w2 = *(const float4*)&Ws[(k + 2) * 64 + c4];
    float4 w3 = *(const float4*)&Ws[(k + 3) * 64 + c4];
    #pragma unroll
    for (int rr = 0; rr < 4; ++rr) {
      float4 xv = *(const float4*)&Xs[(rbase + rr) * 132 + k];
      acc[rr].x = fmaf(xv.x, w0.x, acc[rr].x); acc[rr].y = fmaf(xv.x, w0.y, acc[rr].y);
      acc[rr].z = fmaf(xv.x, w0.z, acc[rr].z); acc[rr].w = fmaf(xv.x, w0.w, acc[rr].w);
      acc[rr].x = fmaf(xv.y, w1.x, acc[rr].x); acc[rr].y = fmaf(xv.y, w1.y, acc[rr].y);
      acc[rr].z = fmaf(xv.y, w1.z, acc[rr].z); acc[rr].w = fmaf(xv.y, w1.w, acc[rr].w);
      acc[rr].x = fmaf(xv.z, w2.x, acc[rr].x); acc[rr].y = fmaf(xv.z, w2.y, acc[rr].y);
      acc[rr].z = fmaf(xv.z, w2.z, acc[rr].z); acc[rr].w = fmaf(xv.z, w2.w, acc[rr].w);
      acc[rr].x = fmaf(xv.w, w3.x, acc[rr].x); acc[rr].y = fmaf(xv.w, w3.y, acc[rr].y);
      acc[rr].z = fmaf(xv.w, w3.z, acc[rr].z); acc[rr].w = fmaf(xv.w, w3.w, acc[rr].w);
    }
  }

  #pragma unroll
  for (int rr = 0; rr < 4; ++rr) {
    int row = row0 + rbase + rr;
    if (row < N) *(float4*)&h[(size_t)row * 64 + c4] = acc[rr];
  }
}

// ---------- atomic-free aggregate + self-term + BN epilogue, one wave per node ----------
__global__ __launch_bounds__(256) void k_aggfinal(const int* __restrict__ off,
                                                  const int* __restrict__ csr,
                                                  const float* __restrict__ isd,
                                                  const float* __restrict__ h,
                                                  const float* __restrict__ gamma,
                                                  const float* __restrict__ beta,
                                                  const float* __restrict__ mean,
                                                  const float* __restrict__ var,
                                                  float* __restrict__ out, int N) {
  int node = blockIdx.x * 4 + (threadIdx.x >> 6);
  int lane = threadIdx.x & 63;
  if (node >= N) return;
  int s = off[node], e2 = off[node + 1];

  float acc = 0.f;
  int d = (s < e2) ? csr[s] : 0;               // prefetch first dst
  for (int p = s; p < e2; ++p) {
    int dn = (p + 1 < e2) ? csr[p + 1] : 0;    // prefetch next while gathering
    acc = fmaf(isd[d], h[(size_t)d * 64 + lane], acc);
    d = dn;
  }

  float hs = h[(size_t)node * 64 + lane];
  float degf = (float)(e2 - s);
  float r = 0.5f * (isd[node] * acc + degf * hs);
  out[(size_t)node * 64 + lane] =
      (r - mean[lane]) * (gamma[lane] * rsqrtf(var[lane] + BN_EPS)) + beta[lane];
}

extern "C" void kernel_launch(void* const* d_in, const int* in_sizes, int n_in,
                              void* d_out, int out_size, void* d_ws, size_t ws_size,
                              hipStream_t stream) {
  const float* X     = (const float*)d_in[0];
  const float* W     = (const float*)d_in[1];
  const float* B     = (const float*)d_in[2];
  const float* gamma = (const float*)d_in[3];
  const float* beta  = (const float*)d_in[4];
  const float* mean  = (const float*)d_in[5];
  const float* var   = (const float*)d_in[6];
  const int2*  ei    = (const int2*)d_in[7];

  int N = in_sizes[0] / 128;
  int E = in_sizes[7] / 2;
  int nb = (N + 1023) / 1024;  // scan blocks

  // workspace layout (all 4B types; h first keeps 16B alignment)
  float* h       = (float*)d_ws;                    // N*64
  int*   csr     = (int*)(h + (size_t)N * 64);      // E
  int*   deg     = csr + E;                         // N
  int*   cursor  = deg + N;                         // N  (adjacent to deg: one memset)
  int*   starts  = cursor + N;                      // N
  int*   blocksum= starts + N;                      // nb
  int*   blockoff= blocksum + nb;                   // nb
  int*   off     = blockoff + nb;                   // N+1
  float* isd     = (float*)(off + N + 1);           // N
  float* out     = (float*)d_out;

  hipMemsetAsync(deg, 0, (size_t)2 * N * sizeof(int), stream);  // deg + cursor

  k_deg<<<(E + 255) / 256, 256, 0, stream>>>(ei, deg, E);
  k_gemm<<<(N + 63) / 64, 256, 0, stream>>>(X, W, B, h, N);
  k_scanA<<<nb, 256, 0, stream>>>(deg, starts, blocksum, isd, N);
  k_scanB<<<1, 256, 0, stream>>>(blocksum, blockoff, nb);
  k_offsets<<<(N + 256) / 256, 256, 0, stream>>>(starts, blockoff, off, N, E);
  k_scatter<<<(E + 255) / 256, 256, 0, stream>>>(ei, off, cursor, csr, E);
  k_aggfinal<<<(N + 3) / 4, 256, 0, stream>>>(off, csr, isd, h, gamma, beta, mean, var, out, N);
}

// Round 4
// 289.104 us; speedup vs baseline: 1.4266x; 1.1444x over previous
//
#include <hip/hip_runtime.h>

#define BN_EPS 0.001f

__device__ __forceinline__ float bf2f(unsigned short u) {
  return __uint_as_float(((unsigned)u) << 16);
}
__device__ __forceinline__ unsigned short f2bf(float f) {
  unsigned u = __float_as_uint(f);
  u += 0x7fffu + ((u >> 16) & 1u);
  return (unsigned short)(u >> 16);
}

// ---------- deg[i] = #edges with src == i ----------
__global__ __launch_bounds__(256) void k_deg(const int2* __restrict__ ei,
                                             int* __restrict__ deg, int E) {
  int e = blockIdx.x * 256 + threadIdx.x;
  if (e < E) atomicAdd(&deg[ei[e].x], 1);
}

// ---------- scan stage A: per-block (1024 elems) local exclusive scan + block totals + isd ----------
__global__ __launch_bounds__(256) void k_scanA(const int* __restrict__ deg,
                                               int* __restrict__ starts,
                                               int* __restrict__ blocksum,
                                               float* __restrict__ isd, int N) {
  __shared__ int sdata[256];
  int tid = threadIdx.x;
  int base = blockIdx.x * 1024 + tid * 4;
  int v0 = 0, v1 = 0, v2 = 0, v3 = 0;
  if (base + 3 < N) {
    int4 d = *(const int4*)&deg[base];
    v0 = d.x; v1 = d.y; v2 = d.z; v3 = d.w;
  } else {
    if (base     < N) v0 = deg[base];
    if (base + 1 < N) v1 = deg[base + 1];
    if (base + 2 < N) v2 = deg[base + 2];
    if (base + 3 < N) v3 = deg[base + 3];
  }
  if (base     < N) isd[base]     = rsqrtf((float)max(v0, 1));
  if (base + 1 < N) isd[base + 1] = rsqrtf((float)max(v1, 1));
  if (base + 2 < N) isd[base + 2] = rsqrtf((float)max(v2, 1));
  if (base + 3 < N) isd[base + 3] = rsqrtf((float)max(v3, 1));

  int s4 = v0 + v1 + v2 + v3;
  sdata[tid] = s4;
  __syncthreads();
  for (int off = 1; off < 256; off <<= 1) {
    int t = (tid >= off) ? sdata[tid - off] : 0;
    __syncthreads();
    sdata[tid] += t;
    __syncthreads();
  }
  int incl = sdata[tid];
  int excl = incl - s4;
  if (tid == 255) blocksum[blockIdx.x] = incl;
  if (base     < N) starts[base]     = excl;
  if (base + 1 < N) starts[base + 1] = excl + v0;
  if (base + 2 < N) starts[base + 2] = excl + v0 + v1;
  if (base + 3 < N) starts[base + 3] = excl + v0 + v1 + v2;
}

// ---------- scan stage B: single-block exclusive scan of block totals ----------
__global__ __launch_bounds__(256) void k_scanB(const int* __restrict__ blocksum,
                                               int* __restrict__ blockoff, int nb) {
  __shared__ int sdata[256];
  int tid = threadIdx.x;
  int carry = 0;
  for (int c0 = 0; c0 < nb; c0 += 256) {
    int i = c0 + tid;
    int v = (i < nb) ? blocksum[i] : 0;
    sdata[tid] = v;
    __syncthreads();
    for (int off = 1; off < 256; off <<= 1) {
      int t = (tid >= off) ? sdata[tid - off] : 0;
      __syncthreads();
      sdata[tid] += t;
      __syncthreads();
    }
    if (i < nb) blockoff[i] = carry + sdata[tid] - v;
    carry += sdata[255];
    __syncthreads();
  }
}

// ---------- scatter edges into CSR-by-src (offsets computed inline) ----------
__global__ __launch_bounds__(256) void k_scatter(const int2* __restrict__ ei,
                                                 const int* __restrict__ starts,
                                                 const int* __restrict__ blockoff,
                                                 int* __restrict__ cursor,
                                                 int* __restrict__ csr, int E) {
  int e = blockIdx.x * 256 + threadIdx.x;
  if (e >= E) return;
  int2 sd = ei[e];
  int base = starts[sd.x] + blockoff[sd.x >> 10];
  int pos = base + atomicAdd(&cursor[sd.x], 1);
  csr[pos] = sd.y;
}

// ---------- h = X @ W + b ; also hb = bf16(isd[row] * h) for the gather ----------
__global__ __launch_bounds__(256) void k_gemm(const float* __restrict__ X,
                                              const float* __restrict__ W,
                                              const float* __restrict__ B,
                                              const float* __restrict__ isd,
                                              float* __restrict__ h,
                                              unsigned short* __restrict__ hb, int N) {
  __shared__ float Ws[128 * 64];   // 32 KB
  __shared__ float Xs[64 * 132];   // 33.8 KB, stride 132 breaks bank conflicts
  int tid = threadIdx.x;

  const float4* W4 = (const float4*)W;
  for (int i = tid; i < 2048; i += 256) *(float4*)&Ws[i * 4] = W4[i];

  int row0 = blockIdx.x * 64;
  const float4* X4 = (const float4*)(X + (size_t)row0 * 128);
  int avail = (N - row0) * 128;
  for (int i = tid * 4; i < 8192; i += 1024) {
    int r = i >> 7, c = i & 127;
    float4 v = (i + 3 < avail) ? X4[i >> 2] : make_float4(0.f, 0.f, 0.f, 0.f);
    *(float4*)&Xs[r * 132 + c] = v;
  }
  __syncthreads();

  int tx = tid & 15, ty = tid >> 4;
  int c4 = tx * 4;
  int rbase = ty * 4;
  float4 bb = *(const float4*)&B[c4];
  float4 acc[4];
  acc[0] = bb; acc[1] = bb; acc[2] = bb; acc[3] = bb;

  #pragma unroll 4
  for (int k = 0; k < 128; k += 4) {
    float4 w0 = *(const float4*)&Ws[(k + 0) * 64 + c4];
    float4 w1 = *(const float4*)&Ws[(k + 1) * 64 + c4];
    float4 w2 = *(const float4*)&Ws[(k + 2) * 64 + c4];
    float4 w3 = *(const float4*)&Ws[(k + 3) * 64 + c4];
    #pragma unroll
    for (int rr = 0; rr < 4; ++rr) {
      float4 xv = *(const float4*)&Xs[(rbase + rr) * 132 + k];
      acc[rr].x = fmaf(xv.x, w0.x, acc[rr].x); acc[rr].y = fmaf(xv.x, w0.y, acc[rr].y);
      acc[rr].z = fmaf(xv.x, w0.z, acc[rr].z); acc[rr].w = fmaf(xv.x, w0.w, acc[rr].w);
      acc[rr].x = fmaf(xv.y, w1.x, acc[rr].x); acc[rr].y = fmaf(xv.y, w1.y, acc[rr].y);
      acc[rr].z = fmaf(xv.y, w1.z, acc[rr].z); acc[rr].w = fmaf(xv.y, w1.w, acc[rr].w);
      acc[rr].x = fmaf(xv.z, w2.x, acc[rr].x); acc[rr].y = fmaf(xv.z, w2.y, acc[rr].y);
      acc[rr].z = fmaf(xv.z, w2.z, acc[rr].z); acc[rr].w = fmaf(xv.z, w2.w, acc[rr].w);
      acc[rr].x = fmaf(xv.w, w3.x, acc[rr].x); acc[rr].y = fmaf(xv.w, w3.y, acc[rr].y);
      acc[rr].z = fmaf(xv.w, w3.z, acc[rr].z); acc[rr].w = fmaf(xv.w, w3.w, acc[rr].w);
    }
  }

  #pragma unroll
  for (int rr = 0; rr < 4; ++rr) {
    int row = row0 + rbase + rr;
    if (row < N) {
      *(float4*)&h[(size_t)row * 64 + c4] = acc[rr];
      float s = isd[row];
      ushort4 hv;
      hv.x = f2bf(s * acc[rr].x); hv.y = f2bf(s * acc[rr].y);
      hv.z = f2bf(s * acc[rr].z); hv.w = f2bf(s * acc[rr].w);
      *(ushort4*)&hb[(size_t)row * 64 + c4] = hv;
    }
  }
}

// ---------- atomic-free aggregate (bf16 pre-scaled gather, unroll x4) + self + BN ----------
__global__ __launch_bounds__(256) void k_aggfinal(const int* __restrict__ starts,
                                                  const int* __restrict__ blockoff,
                                                  const int* __restrict__ csr,
                                                  const float* __restrict__ isd,
                                                  const float* __restrict__ h,
                                                  const unsigned short* __restrict__ hb,
                                                  const float* __restrict__ gamma,
                                                  const float* __restrict__ beta,
                                                  const float* __restrict__ mean,
                                                  const float* __restrict__ var,
                                                  float* __restrict__ out, int N, int E) {
  int node = blockIdx.x * 4 + (threadIdx.x >> 6);
  int lane = threadIdx.x & 63;
  if (node >= N) return;
  int s  = starts[node] + blockoff[node >> 10];
  int e2 = (node + 1 < N) ? (starts[node + 1] + blockoff[(node + 1) >> 10]) : E;

  float acc = 0.f;
  int p = s;
  for (; p + 4 <= e2; p += 4) {
    int d0 = csr[p], d1 = csr[p + 1], d2 = csr[p + 2], d3 = csr[p + 3];
    float v0 = bf2f(hb[(size_t)d0 * 64 + lane]);
    float v1 = bf2f(hb[(size_t)d1 * 64 + lane]);
    float v2 = bf2f(hb[(size_t)d2 * 64 + lane]);
    float v3 = bf2f(hb[(size_t)d3 * 64 + lane]);
    acc += (v0 + v1) + (v2 + v3);
  }
  for (; p < e2; ++p) {
    acc += bf2f(hb[(size_t)csr[p] * 64 + lane]);
  }

  float hs = h[(size_t)node * 64 + lane];
  float degf = (float)(e2 - s);
  float r = 0.5f * (isd[node] * acc + degf * hs);
  out[(size_t)node * 64 + lane] =
      (r - mean[lane]) * (gamma[lane] * rsqrtf(var[lane] + BN_EPS)) + beta[lane];
}

extern "C" void kernel_launch(void* const* d_in, const int* in_sizes, int n_in,
                              void* d_out, int out_size, void* d_ws, size_t ws_size,
                              hipStream_t stream) {
  const float* X     = (const float*)d_in[0];
  const float* W     = (const float*)d_in[1];
  const float* B     = (const float*)d_in[2];
  const float* gamma = (const float*)d_in[3];
  const float* beta  = (const float*)d_in[4];
  const float* mean  = (const float*)d_in[5];
  const float* var   = (const float*)d_in[6];
  const int2*  ei    = (const int2*)d_in[7];

  int N = in_sizes[0] / 128;
  int E = in_sizes[7] / 2;
  int nb = (N + 1023) / 1024;  // scan blocks

  // workspace layout
  float*          h       = (float*)d_ws;                       // N*64 f32
  unsigned short* hb      = (unsigned short*)(h + (size_t)N * 64); // N*64 bf16
  int*            csr     = (int*)(hb + (size_t)N * 64);        // E
  int*            deg     = csr + E;                            // N
  int*            cursor  = deg + N;                            // N (adjacent: one memset)
  int*            starts  = cursor + N;                         // N
  int*            blocksum= starts + N;                         // nb
  int*            blockoff= blocksum + nb;                      // nb
  float*          isd     = (float*)(blockoff + nb);            // N
  float*          out     = (float*)d_out;

  hipMemsetAsync(deg, 0, (size_t)2 * N * sizeof(int), stream);  // deg + cursor

  k_deg<<<(E + 255) / 256, 256, 0, stream>>>(ei, deg, E);
  k_scanA<<<nb, 256, 0, stream>>>(deg, starts, blocksum, isd, N);
  k_scanB<<<1, 256, 0, stream>>>(blocksum, blockoff, nb);
  k_gemm<<<(N + 63) / 64, 256, 0, stream>>>(X, W, B, isd, h, hb, N);
  k_scatter<<<(E + 255) / 256, 256, 0, stream>>>(ei, starts, blockoff, cursor, csr, E);
  k_aggfinal<<<(N + 3) / 4, 256, 0, stream>>>(starts, blockoff, csr, isd, h, hb,
                                              gamma, beta, mean, var, out, N, E);
}

// Round 5
// 269.704 us; speedup vs baseline: 1.5293x; 1.0719x over previous
//
#include <hip/hip_runtime.h>

#define BN_EPS 0.001f

__device__ __forceinline__ float bf2f(unsigned short u) {
  return __uint_as_float(((unsigned)u) << 16);
}
__device__ __forceinline__ unsigned short f2bf(float f) {
  unsigned u = __float_as_uint(f);
  u += 0x7fffu + ((u >> 16) & 1u);
  return (unsigned short)(u >> 16);
}

// ---------- deg[i] = #edges with src == i ----------
__global__ __launch_bounds__(256) void k_deg(const int2* __restrict__ ei,
                                             int* __restrict__ deg, int E) {
  int e = blockIdx.x * 256 + threadIdx.x;
  if (e < E) atomicAdd(&deg[ei[e].x], 1);
}

// ---------- scan stage A: per-block (1024 elems) local exclusive scan + block totals + isd ----------
__global__ __launch_bounds__(256) void k_scanA(const int* __restrict__ deg,
                                               int* __restrict__ starts,
                                               int* __restrict__ blocksum,
                                               float* __restrict__ isd, int N) {
  __shared__ int sdata[256];
  int tid = threadIdx.x;
  int base = blockIdx.x * 1024 + tid * 4;
  int v0 = 0, v1 = 0, v2 = 0, v3 = 0;
  if (base + 3 < N) {
    int4 d = *(const int4*)&deg[base];
    v0 = d.x; v1 = d.y; v2 = d.z; v3 = d.w;
  } else {
    if (base     < N) v0 = deg[base];
    if (base + 1 < N) v1 = deg[base + 1];
    if (base + 2 < N) v2 = deg[base + 2];
    if (base + 3 < N) v3 = deg[base + 3];
  }
  if (base     < N) isd[base]     = rsqrtf((float)max(v0, 1));
  if (base + 1 < N) isd[base + 1] = rsqrtf((float)max(v1, 1));
  if (base + 2 < N) isd[base + 2] = rsqrtf((float)max(v2, 1));
  if (base + 3 < N) isd[base + 3] = rsqrtf((float)max(v3, 1));

  int s4 = v0 + v1 + v2 + v3;
  sdata[tid] = s4;
  __syncthreads();
  for (int off = 1; off < 256; off <<= 1) {
    int t = (tid >= off) ? sdata[tid - off] : 0;
    __syncthreads();
    sdata[tid] += t;
    __syncthreads();
  }
  int incl = sdata[tid];
  int excl = incl - s4;
  if (tid == 255) blocksum[blockIdx.x] = incl;
  if (base     < N) starts[base]     = excl;
  if (base + 1 < N) starts[base + 1] = excl + v0;
  if (base + 2 < N) starts[base + 2] = excl + v0 + v1;
  if (base + 3 < N) starts[base + 3] = excl + v0 + v1 + v2;
}

// ---------- scan stage B: single-block exclusive scan of block totals ----------
__global__ __launch_bounds__(256) void k_scanB(const int* __restrict__ blocksum,
                                               int* __restrict__ blockoff, int nb) {
  __shared__ int sdata[256];
  int tid = threadIdx.x;
  int carry = 0;
  for (int c0 = 0; c0 < nb; c0 += 256) {
    int i = c0 + tid;
    int v = (i < nb) ? blocksum[i] : 0;
    sdata[tid] = v;
    __syncthreads();
    for (int off = 1; off < 256; off <<= 1) {
      int t = (tid >= off) ? sdata[tid - off] : 0;
      __syncthreads();
      sdata[tid] += t;
      __syncthreads();
    }
    if (i < nb) blockoff[i] = carry + sdata[tid] - v;
    carry += sdata[255];
    __syncthreads();
  }
}

// ---------- FUSED: gemm tiles + edge scatter, interleaved 2:5 per 7 blocks ----------
// gemm role:    h = X @ W + b ; hb = bf16(isd[row] * h)   (VALU/LDS-bound)
// scatter role: csr[off[src] + cursor[src]++] = dst        (memory-latency-bound)
__global__ __launch_bounds__(256) void k_fused(
    const float* __restrict__ X, const float* __restrict__ W,
    const float* __restrict__ B, const float* __restrict__ isd,
    float* __restrict__ h, unsigned short* __restrict__ hb, int N, int Gg,
    const int2* __restrict__ ei, const int* __restrict__ starts,
    const int* __restrict__ blockoff, int* __restrict__ cursor,
    int* __restrict__ csr, int E, int Gs) {
  __shared__ float Ws[128 * 64];   // 32 KB
  __shared__ float Xs[64 * 132];   // 33.8 KB, stride 132 breaks bank conflicts

  int g = blockIdx.x / 7;
  int r = blockIdx.x % 7;

  if (r >= 2) {
    // ----- scatter role -----
    int chunk = g * 5 + (r - 2);
    if (chunk >= Gs) return;
    int e = chunk * 256 + threadIdx.x;
    if (e < E) {
      int2 sd = ei[e];
      int base = starts[sd.x] + blockoff[sd.x >> 10];
      int pos = base + atomicAdd(&cursor[sd.x], 1);
      csr[pos] = sd.y;
    }
    return;
  }

  // ----- gemm role -----
  int tile = g * 2 + r;
  if (tile >= Gg) return;
  int tid = threadIdx.x;

  const float4* W4 = (const float4*)W;
  for (int i = tid; i < 2048; i += 256) *(float4*)&Ws[i * 4] = W4[i];

  int row0 = tile * 64;
  const float4* X4 = (const float4*)(X + (size_t)row0 * 128);
  int avail = (N - row0) * 128;
  for (int i = tid * 4; i < 8192; i += 1024) {
    int rr = i >> 7, c = i & 127;
    float4 v = (i + 3 < avail) ? X4[i >> 2] : make_float4(0.f, 0.f, 0.f, 0.f);
    *(float4*)&Xs[rr * 132 + c] = v;
  }
  __syncthreads();

  int tx = tid & 15, ty = tid >> 4;
  int c4 = tx * 4;
  int rbase = ty * 4;
  float4 bb = *(const float4*)&B[c4];
  float4 acc[4];
  acc[0] = bb; acc[1] = bb; acc[2] = bb; acc[3] = bb;

  #pragma unroll 4
  for (int k = 0; k < 128; k += 4) {
    float4 w0 = *(const float4*)&Ws[(k + 0) * 64 + c4];
    float4 w1 = *(const float4*)&Ws[(k + 1) * 64 + c4];
    float4 w2 = *(const float4*)&Ws[(k + 2) * 64 + c4];
    float4 w3 = *(const float4*)&Ws[(k + 3) * 64 + c4];
    #pragma unroll
    for (int rr = 0; rr < 4; ++rr) {
      float4 xv = *(const float4*)&Xs[(rbase + rr) * 132 + k];
      acc[rr].x = fmaf(xv.x, w0.x, acc[rr].x); acc[rr].y = fmaf(xv.x, w0.y, acc[rr].y);
      acc[rr].z = fmaf(xv.x, w0.z, acc[rr].z); acc[rr].w = fmaf(xv.x, w0.w, acc[rr].w);
      acc[rr].x = fmaf(xv.y, w1.x, acc[rr].x); acc[rr].y = fmaf(xv.y, w1.y, acc[rr].y);
      acc[rr].z = fmaf(xv.y, w1.z, acc[rr].z); acc[rr].w = fmaf(xv.y, w1.w, acc[rr].w);
      acc[rr].x = fmaf(xv.z, w2.x, acc[rr].x); acc[rr].y = fmaf(xv.z, w2.y, acc[rr].y);
      acc[rr].z = fmaf(xv.z, w2.z, acc[rr].z); acc[rr].w = fmaf(xv.z, w2.w, acc[rr].w);
      acc[rr].x = fmaf(xv.w, w3.x, acc[rr].x); acc[rr].y = fmaf(xv.w, w3.y, acc[rr].y);
      acc[rr].z = fmaf(xv.w, w3.z, acc[rr].z); acc[rr].w = fmaf(xv.w, w3.w, acc[rr].w);
    }
  }

  #pragma unroll
  for (int rr = 0; rr < 4; ++rr) {
    int row = row0 + rbase + rr;
    if (row < N) {
      *(float4*)&h[(size_t)row * 64 + c4] = acc[rr];
      float s = isd[row];
      ushort4 hv;
      hv.x = f2bf(s * acc[rr].x); hv.y = f2bf(s * acc[rr].y);
      hv.z = f2bf(s * acc[rr].z); hv.w = f2bf(s * acc[rr].w);
      *(ushort4*)&hb[(size_t)row * 64 + c4] = hv;
    }
  }
}

// ---------- atomic-free aggregate (bf16 pre-scaled gather, unroll x4) + self + BN ----------
__global__ __launch_bounds__(256) void k_aggfinal(const int* __restrict__ starts,
                                                  const int* __restrict__ blockoff,
                                                  const int* __restrict__ csr,
                                                  const float* __restrict__ isd,
                                                  const float* __restrict__ h,
                                                  const unsigned short* __restrict__ hb,
                                                  const float* __restrict__ gamma,
                                                  const float* __restrict__ beta,
                                                  const float* __restrict__ mean,
                                                  const float* __restrict__ var,
                                                  float* __restrict__ out, int N, int E) {
  int node = blockIdx.x * 4 + (threadIdx.x >> 6);
  int lane = threadIdx.x & 63;
  if (node >= N) return;
  int s  = starts[node] + blockoff[node >> 10];
  int e2 = (node + 1 < N) ? (starts[node + 1] + blockoff[(node + 1) >> 10]) : E;

  float acc = 0.f;
  int p = s;
  for (; p + 4 <= e2; p += 4) {
    int d0 = csr[p], d1 = csr[p + 1], d2 = csr[p + 2], d3 = csr[p + 3];
    float v0 = bf2f(hb[(size_t)d0 * 64 + lane]);
    float v1 = bf2f(hb[(size_t)d1 * 64 + lane]);
    float v2 = bf2f(hb[(size_t)d2 * 64 + lane]);
    float v3 = bf2f(hb[(size_t)d3 * 64 + lane]);
    acc += (v0 + v1) + (v2 + v3);
  }
  for (; p < e2; ++p) {
    acc += bf2f(hb[(size_t)csr[p] * 64 + lane]);
  }

  float hs = h[(size_t)node * 64 + lane];
  float degf = (float)(e2 - s);
  float r = 0.5f * (isd[node] * acc + degf * hs);
  out[(size_t)node * 64 + lane] =
      (r - mean[lane]) * (gamma[lane] * rsqrtf(var[lane] + BN_EPS)) + beta[lane];
}

extern "C" void kernel_launch(void* const* d_in, const int* in_sizes, int n_in,
                              void* d_out, int out_size, void* d_ws, size_t ws_size,
                              hipStream_t stream) {
  const float* X     = (const float*)d_in[0];
  const float* W     = (const float*)d_in[1];
  const float* B     = (const float*)d_in[2];
  const float* gamma = (const float*)d_in[3];
  const float* beta  = (const float*)d_in[4];
  const float* mean  = (const float*)d_in[5];
  const float* var   = (const float*)d_in[6];
  const int2*  ei    = (const int2*)d_in[7];

  int N = in_sizes[0] / 128;
  int E = in_sizes[7] / 2;
  int nb = (N + 1023) / 1024;  // scan blocks

  // workspace layout
  float*          h       = (float*)d_ws;                          // N*64 f32
  unsigned short* hb      = (unsigned short*)(h + (size_t)N * 64); // N*64 bf16
  int*            csr     = (int*)(hb + (size_t)N * 64);           // E
  int*            deg     = csr + E;                               // N
  int*            cursor  = deg + N;                               // N (adjacent: one memset)
  int*            starts  = cursor + N;                            // N
  int*            blocksum= starts + N;                            // nb
  int*            blockoff= blocksum + nb;                         // nb
  float*          isd     = (float*)(blockoff + nb);               // N
  float*          out     = (float*)d_out;

  hipMemsetAsync(deg, 0, (size_t)2 * N * sizeof(int), stream);  // deg + cursor

  k_deg<<<(E + 255) / 256, 256, 0, stream>>>(ei, deg, E);
  k_scanA<<<nb, 256, 0, stream>>>(deg, starts, blocksum, isd, N);
  k_scanB<<<1, 256, 0, stream>>>(blocksum, blockoff, nb);

  int Gg = (N + 63) / 64;        // gemm tiles      (1563)
  int Gs = (E + 255) / 256;      // scatter chunks  (3907)
  int g7 = (Gg + 1) / 2;
  int g5 = (Gs + 4) / 5;
  int groups = (g7 > g5) ? g7 : g5;
  int T = groups * 7;            // 2 gemm + 5 scatter per group of 7 blocks
  k_fused<<<T, 256, 0, stream>>>(X, W, B, isd, h, hb, N, Gg,
                                 ei, starts, blockoff, cursor, csr, E, Gs);

  k_aggfinal<<<(N + 3) / 4, 256, 0, stream>>>(starts, blockoff, csr, isd, h, hb,
                                              gamma, beta, mean, var, out, N, E);
}

// Round 6
// 262.039 us; speedup vs baseline: 1.5740x; 1.0292x over previous
//
#include <hip/hip_runtime.h>

#define BN_EPS 0.001f

__device__ __forceinline__ float bf2f(unsigned short u) {
  return __uint_as_float(((unsigned)u) << 16);
}
__device__ __forceinline__ unsigned short f2bf(float f) {
  unsigned u = __float_as_uint(f);
  u += 0x7fffu + ((u >> 16) & 1u);
  return (unsigned short)(u >> 16);
}

// ---------- deg, 8-way shadow histograms to cut atomic same-line contention ----------
__global__ __launch_bounds__(256) void k_deg(const int2* __restrict__ ei,
                                             int* __restrict__ deg8, int N8, int E) {
  int e = blockIdx.x * 256 + threadIdx.x;
  int part = blockIdx.x & 7;
  if (e < E) atomicAdd(&deg8[part * N8 + ei[e].x], 1);
}

// ---------- scan stage A: sum 8 partials, local excl scan (1024/block), block totals, isd ----------
__global__ __launch_bounds__(256) void k_scanA(const int* __restrict__ deg8, int N8,
                                               int* __restrict__ starts,
                                               int* __restrict__ blocksum,
                                               float* __restrict__ isd, int N) {
  __shared__ int sdata[256];
  int tid = threadIdx.x;
  int base = blockIdx.x * 1024 + tid * 4;
  int v0 = 0, v1 = 0, v2 = 0, v3 = 0;
  if (base + 3 < N) {
    #pragma unroll
    for (int j = 0; j < 8; ++j) {
      int4 d = *(const int4*)&deg8[j * N8 + base];
      v0 += d.x; v1 += d.y; v2 += d.z; v3 += d.w;
    }
  } else if (base < N) {
    #pragma unroll
    for (int j = 0; j < 8; ++j) {
      const int* dj = &deg8[j * N8];
      v0 += dj[base];
      if (base + 1 < N) v1 += dj[base + 1];
      if (base + 2 < N) v2 += dj[base + 2];
      if (base + 3 < N) v3 += dj[base + 3];
    }
  }
  if (base     < N) isd[base]     = rsqrtf((float)max(v0, 1));
  if (base + 1 < N) isd[base + 1] = rsqrtf((float)max(v1, 1));
  if (base + 2 < N) isd[base + 2] = rsqrtf((float)max(v2, 1));
  if (base + 3 < N) isd[base + 3] = rsqrtf((float)max(v3, 1));

  int s4 = v0 + v1 + v2 + v3;
  sdata[tid] = s4;
  __syncthreads();
  for (int off = 1; off < 256; off <<= 1) {
    int t = (tid >= off) ? sdata[tid - off] : 0;
    __syncthreads();
    sdata[tid] += t;
    __syncthreads();
  }
  int incl = sdata[tid];
  int excl = incl - s4;
  if (tid == 255) blocksum[blockIdx.x] = incl;
  if (base     < N) starts[base]     = excl;
  if (base + 1 < N) starts[base + 1] = excl + v0;
  if (base + 2 < N) starts[base + 2] = excl + v0 + v1;
  if (base + 3 < N) starts[base + 3] = excl + v0 + v1 + v2;
}

// ---------- scan stage B: single-block exclusive scan of block totals ----------
__global__ __launch_bounds__(256) void k_scanB(const int* __restrict__ blocksum,
                                               int* __restrict__ blockoff, int nb) {
  __shared__ int sdata[256];
  int tid = threadIdx.x;
  int carry = 0;
  for (int c0 = 0; c0 < nb; c0 += 256) {
    int i = c0 + tid;
    int v = (i < nb) ? blocksum[i] : 0;
    sdata[tid] = v;
    __syncthreads();
    for (int off = 1; off < 256; off <<= 1) {
      int t = (tid >= off) ? sdata[tid - off] : 0;
      __syncthreads();
      sdata[tid] += t;
      __syncthreads();
    }
    if (i < nb) blockoff[i] = carry + sdata[tid] - v;
    carry += sdata[255];
    __syncthreads();
  }
}

// ---------- FUSED: gemm tiles + edge scatter, interleaved 2:5 per 7 blocks ----------
// LDS = 32K (Ws fp32) + 16.9K (Xs bf16) = 48.9K -> 3 blocks/CU (was 2)
__global__ __launch_bounds__(256) void k_fused(
    const float* __restrict__ X, const float* __restrict__ W,
    const float* __restrict__ B, const float* __restrict__ isd,
    float* __restrict__ h, unsigned short* __restrict__ hb, int N, int Gg,
    const int2* __restrict__ ei, const int* __restrict__ starts,
    const int* __restrict__ blockoff, int* __restrict__ cursor,
    int* __restrict__ csr, int E, int Gs) {
  __shared__ float Ws[128 * 64];            // 32 KB
  __shared__ unsigned short Xs[64 * 132];   // 16.9 KB bf16, stride 132

  int g = blockIdx.x / 7;
  int r = blockIdx.x % 7;

  if (r >= 2) {
    // ----- scatter role -----
    int chunk = g * 5 + (r - 2);
    if (chunk >= Gs) return;
    int e = chunk * 256 + threadIdx.x;
    if (e < E) {
      int2 sd = ei[e];
      int base = starts[sd.x] + blockoff[sd.x >> 10];
      int pos = base + atomicAdd(&cursor[sd.x], 1);
      csr[pos] = sd.y;
    }
    return;
  }

  // ----- gemm role -----
  int tile = g * 2 + r;
  if (tile >= Gg) return;
  int tid = threadIdx.x;

  const float4* W4 = (const float4*)W;
  for (int i = tid; i < 2048; i += 256) *(float4*)&Ws[i * 4] = W4[i];

  int row0 = tile * 64;
  const float4* X4 = (const float4*)(X + (size_t)row0 * 128);
  int avail = (N - row0) * 128;
  for (int i = tid * 4; i < 8192; i += 1024) {
    int rr = i >> 7, c = i & 127;
    float4 v = (i + 3 < avail) ? X4[i >> 2] : make_float4(0.f, 0.f, 0.f, 0.f);
    ushort4 bv;
    bv.x = f2bf(v.x); bv.y = f2bf(v.y); bv.z = f2bf(v.z); bv.w = f2bf(v.w);
    *(ushort4*)&Xs[rr * 132 + c] = bv;
  }
  __syncthreads();

  int tx = tid & 15, ty = tid >> 4;
  int c4 = tx * 4;
  int rbase = ty * 4;
  float4 bb = *(const float4*)&B[c4];
  float4 acc[4];
  acc[0] = bb; acc[1] = bb; acc[2] = bb; acc[3] = bb;

  #pragma unroll 4
  for (int k = 0; k < 128; k += 4) {
    float4 w0 = *(const float4*)&Ws[(k + 0) * 64 + c4];
    float4 w1 = *(const float4*)&Ws[(k + 1) * 64 + c4];
    float4 w2 = *(const float4*)&Ws[(k + 2) * 64 + c4];
    float4 w3 = *(const float4*)&Ws[(k + 3) * 64 + c4];
    #pragma unroll
    for (int rr = 0; rr < 4; ++rr) {
      ushort4 xu = *(const ushort4*)&Xs[(rbase + rr) * 132 + k];
      float xvx = bf2f(xu.x), xvy = bf2f(xu.y), xvz = bf2f(xu.z), xvw = bf2f(xu.w);
      acc[rr].x = fmaf(xvx, w0.x, acc[rr].x); acc[rr].y = fmaf(xvx, w0.y, acc[rr].y);
      acc[rr].z = fmaf(xvx, w0.z, acc[rr].z); acc[rr].w = fmaf(xvx, w0.w, acc[rr].w);
      acc[rr].x = fmaf(xvy, w1.x, acc[rr].x); acc[rr].y = fmaf(xvy, w1.y, acc[rr].y);
      acc[rr].z = fmaf(xvy, w1.z, acc[rr].z); acc[rr].w = fmaf(xvy, w1.w, acc[rr].w);
      acc[rr].x = fmaf(xvz, w2.x, acc[rr].x); acc[rr].y = fmaf(xvz, w2.y, acc[rr].y);
      acc[rr].z = fmaf(xvz, w2.z, acc[rr].z); acc[rr].w = fmaf(xvz, w2.w, acc[rr].w);
      acc[rr].x = fmaf(xvw, w3.x, acc[rr].x); acc[rr].y = fmaf(xvw, w3.y, acc[rr].y);
      acc[rr].z = fmaf(xvw, w3.z, acc[rr].z); acc[rr].w = fmaf(xvw, w3.w, acc[rr].w);
    }
  }

  #pragma unroll
  for (int rr = 0; rr < 4; ++rr) {
    int row = row0 + rbase + rr;
    if (row < N) {
      *(float4*)&h[(size_t)row * 64 + c4] = acc[rr];
      float s = isd[row];
      ushort4 hv;
      hv.x = f2bf(s * acc[rr].x); hv.y = f2bf(s * acc[rr].y);
      hv.z = f2bf(s * acc[rr].z); hv.w = f2bf(s * acc[rr].w);
      *(ushort4*)&hb[(size_t)row * 64 + c4] = hv;
    }
  }
}

// ---------- atomic-free aggregate (bf16 pre-scaled gather, unroll x4) + self + BN ----------
__global__ __launch_bounds__(256) void k_aggfinal(const int* __restrict__ starts,
                                                  const int* __restrict__ blockoff,
                                                  const int* __restrict__ csr,
                                                  const float* __restrict__ isd,
                                                  const float* __restrict__ h,
                                                  const unsigned short* __restrict__ hb,
                                                  const float* __restrict__ gamma,
                                                  const float* __restrict__ beta,
                                                  const float* __restrict__ mean,
                                                  const float* __restrict__ var,
                                                  float* __restrict__ out, int N, int E) {
  int node = blockIdx.x * 4 + (threadIdx.x >> 6);
  int lane = threadIdx.x & 63;
  if (node >= N) return;
  int s  = starts[node] + blockoff[node >> 10];
  int e2 = (node + 1 < N) ? (starts[node + 1] + blockoff[(node + 1) >> 10]) : E;

  float acc = 0.f;
  int p = s;
  for (; p + 4 <= e2; p += 4) {
    int d0 = csr[p], d1 = csr[p + 1], d2 = csr[p + 2], d3 = csr[p + 3];
    float v0 = bf2f(hb[(size_t)d0 * 64 + lane]);
    float v1 = bf2f(hb[(size_t)d1 * 64 + lane]);
    float v2 = bf2f(hb[(size_t)d2 * 64 + lane]);
    float v3 = bf2f(hb[(size_t)d3 * 64 + lane]);
    acc += (v0 + v1) + (v2 + v3);
  }
  for (; p < e2; ++p) {
    acc += bf2f(hb[(size_t)csr[p] * 64 + lane]);
  }

  float hs = h[(size_t)node * 64 + lane];
  float degf = (float)(e2 - s);
  float r = 0.5f * (isd[node] * acc + degf * hs);
  out[(size_t)node * 64 + lane] =
      (r - mean[lane]) * (gamma[lane] * rsqrtf(var[lane] + BN_EPS)) + beta[lane];
}

extern "C" void kernel_launch(void* const* d_in, const int* in_sizes, int n_in,
                              void* d_out, int out_size, void* d_ws, size_t ws_size,
                              hipStream_t stream) {
  const float* X     = (const float*)d_in[0];
  const float* W     = (const float*)d_in[1];
  const float* B     = (const float*)d_in[2];
  const float* gamma = (const float*)d_in[3];
  const float* beta  = (const float*)d_in[4];
  const float* mean  = (const float*)d_in[5];
  const float* var   = (const float*)d_in[6];
  const int2*  ei    = (const int2*)d_in[7];

  int N = in_sizes[0] / 128;
  int E = in_sizes[7] / 2;
  int nb = (N + 1023) / 1024;          // scan blocks
  int N8 = (N + 255) & ~255;           // shadow-histogram stride

  // workspace layout
  float*          h       = (float*)d_ws;                          // N*64 f32
  unsigned short* hb      = (unsigned short*)(h + (size_t)N * 64); // N*64 bf16
  int*            csr     = (int*)(hb + (size_t)N * 64);           // E
  int*            deg8    = csr + E;                               // 8*N8
  int*            cursor  = deg8 + (size_t)8 * N8;                 // N (adjacent: one memset)
  int*            starts  = cursor + N;                            // N
  int*            blocksum= starts + N;                            // nb
  int*            blockoff= blocksum + nb;                         // nb
  float*          isd     = (float*)(blockoff + nb);               // N
  float*          out     = (float*)d_out;

  hipMemsetAsync(deg8, 0, ((size_t)8 * N8 + N) * sizeof(int), stream);  // deg8 + cursor

  k_deg<<<(E + 255) / 256, 256, 0, stream>>>(ei, deg8, N8, E);
  k_scanA<<<nb, 256, 0, stream>>>(deg8, N8, starts, blocksum, isd, N);
  k_scanB<<<1, 256, 0, stream>>>(blocksum, blockoff, nb);

  int Gg = (N + 63) / 64;        // gemm tiles      (1563)
  int Gs = (E + 255) / 256;      // scatter chunks  (3907)
  int g7 = (Gg + 1) / 2;
  int g5 = (Gs + 4) / 5;
  int groups = (g7 > g5) ? g7 : g5;
  int T = groups * 7;            // 2 gemm + 5 scatter per group of 7 blocks
  k_fused<<<T, 256, 0, stream>>>(X, W, B, isd, h, hb, N, Gg,
                                 ei, starts, blockoff, cursor, csr, E, Gs);

  k_aggfinal<<<(N + 3) / 4, 256, 0, stream>>>(starts, blockoff, csr, isd, h, hb,
                                              gamma, beta, mean, var, out, N, E);
}